// Round 3
// baseline (395.687 us; speedup 1.0000x reference)
//
#include <hip/hip_runtime.h>
#include <stdint.h>

#define B_ 2
#define T_ 4096
#define D_ 512
#define H_ 8
#define DH_ 64

typedef __bf16 bf16;
typedef __bf16 bf16x4_t __attribute__((ext_vector_type(4)));
typedef __bf16 bf16x8_t __attribute__((ext_vector_type(8)));
typedef float f32x4 __attribute__((ext_vector_type(4)));
typedef short short4_t __attribute__((ext_vector_type(4)));
typedef uint32_t u32;

static constexpr float QSCALE = 0.18033688011112042f;   // log2(e)/8 (folded into Wq,bq)

__device__ __forceinline__ void async16(void* lds, const void* g) {
  __builtin_amdgcn_global_load_lds(
      (const __attribute__((address_space(1))) void*)g,
      (__attribute__((address_space(3))) void*)lds, 16, 0, 0);
}

// ---------------------------------------------------------------- prep ----
__global__ __launch_bounds__(256) void prep_kernel(
    const float* __restrict__ x,
    const float* __restrict__ Wq, const float* __restrict__ Wk,
    const float* __restrict__ Wv, const float* __restrict__ Wo,
    const void* __restrict__ maskp,
    bf16* __restrict__ xb, bf16* __restrict__ WTall, bf16* __restrict__ WoT,
    u32* __restrict__ bmask)
{
  int bid = blockIdx.x;
  int tid = threadIdx.x;
  if (bid < 4096) {
    int idx = bid * 256 + tid;
    const float4* xf = (const float4*)x;
    float4 v = xf[idx];
    bf16x4_t o;
    o[0] = (bf16)v.x; o[1] = (bf16)v.y; o[2] = (bf16)v.z; o[3] = (bf16)v.w;
    ((bf16x4_t*)xb)[idx] = o;
  } else if (bid < 8192) {
    int gid = (bid - 4096) * 256 + tid;
    int sel = gid >> 18;
    int idx = gid & 262143;
    int n = idx >> 9, k = idx & 511;
    if (sel < 3) {
      const float* W = (sel == 0) ? Wq : (sel == 1) ? Wk : Wv;
      float v = W[k * 512 + n];
      if (sel == 0) v *= QSCALE;
      WTall[gid] = (bf16)v;
    } else {
      WoT[idx] = (bf16)Wo[k * 512 + n];
    }
  } else {
    int wid = (bid - 8192) * 256 + tid;   // 524,288 words
    const uint8_t* m8 = (const uint8_t*)maskp;
    bool u8mode = (__ballot(m8[4 * (tid & 63) + 1] != 0) != 0ull);
    int row = wid >> 7, wcol = wid & 127;
    size_t off = (size_t)row * 4096 + (size_t)wcol * 32;
    u32 w = 0;
    if (u8mode) {
      const uint4* p = (const uint4*)(m8 + off);
      uint4 a = p[0], b = p[1];
      u32 ws[8] = {a.x, a.y, a.z, a.w, b.x, b.y, b.z, b.w};
      #pragma unroll
      for (int j = 0; j < 32; ++j)
        if ((ws[j >> 2] >> ((j & 3) * 8)) & 0xffu) w |= (1u << j);
    } else {
      const uint4* p = (const uint4*)((const u32*)maskp + off);
      #pragma unroll
      for (int q = 0; q < 8; ++q) {
        uint4 a = p[q];
        if (a.x) w |= 1u << (q * 4 + 0);
        if (a.y) w |= 1u << (q * 4 + 1);
        if (a.z) w |= 1u << (q * 4 + 2);
        if (a.w) w |= 1u << (q * 4 + 3);
      }
    }
    bmask[((size_t)(row >> 6) * 64 + (wcol >> 1)) * 128 + (row & 63) * 2 + (wcol & 1)] = w;
  }
}

// ---------------------------------------------------------- QKV GEMM -------
// 128x128 tiles: 4 waves, each owns a 64x64 sub-tile. BK=64, 2-barrier.
__global__ __launch_bounds__(256) void qkv_kernel(
    const bf16* __restrict__ xb, const bf16* __restrict__ WTall,
    const float* __restrict__ bq, const float* __restrict__ bk,
    const float* __restrict__ bv,
    bf16* __restrict__ Qb, bf16* __restrict__ Kb, bf16* __restrict__ Vtb)
{
  __shared__ char smem[32768];
  char* smX = smem;                 // 128 rows x 128B (swizzled)
  char* smW = smem + 16384;         // 128 rows x 128B
  int tid = threadIdx.x;
  int lane = tid & 63, wave = tid >> 6;
  int lo = lane & 15, quad = lane >> 4;
  int wr = wave >> 1, wc = wave & 1;
  int bm = blockIdx.x * 128;
  int bn = blockIdx.y * 128;
  int sel = bn >> 9;   // 0=Q 1=K 2=V
  f32x4 acc[4][4] = {};
  for (int kc = 0; kc < 8; ++kc) {
    __syncthreads();
    #pragma unroll
    for (int i = 0; i < 4; ++i) {
      int s = tid + i * 256;
      int row = s >> 3, slot = s & 7;
      int cg = slot ^ (row & 7) ^ ((row >> 3) & 1);
      async16(smX + s * 16, xb + (size_t)(bm + row) * 512 + kc * 64 + cg * 8);
      async16(smW + s * 16, WTall + (size_t)(bn + row) * 512 + kc * 64 + cg * 8);
    }
    __syncthreads();
    #pragma unroll
    for (int ks = 0; ks < 2; ++ks) {
      bf16x8_t a[4], b[4];
      #pragma unroll
      for (int mt = 0; mt < 4; ++mt) {
        int row = wr * 64 + mt * 16 + lo;
        int ch = (ks * 4 + quad) ^ (row & 7) ^ ((row >> 3) & 1);
        a[mt] = *(const bf16x8_t*)(smX + row * 128 + ch * 16);
      }
      #pragma unroll
      for (int nt = 0; nt < 4; ++nt) {
        int row = wc * 64 + nt * 16 + lo;
        int ch = (ks * 4 + quad) ^ (row & 7) ^ ((row >> 3) & 1);
        b[nt] = *(const bf16x8_t*)(smW + row * 128 + ch * 16);
      }
      if (sel < 2) {
        #pragma unroll
        for (int mt = 0; mt < 4; ++mt)
          #pragma unroll
          for (int nt = 0; nt < 4; ++nt)
            acc[mt][nt] = __builtin_amdgcn_mfma_f32_16x16x32_bf16(
                b[nt], a[mt], acc[mt][nt], 0, 0, 0);   // D: m=W-row, n=t
      } else {
        #pragma unroll
        for (int mt = 0; mt < 4; ++mt)
          #pragma unroll
          for (int nt = 0; nt < 4; ++nt)
            acc[mt][nt] = __builtin_amdgcn_mfma_f32_16x16x32_bf16(
                a[mt], b[nt], acc[mt][nt], 0, 0, 0);   // D: m=t, n=W-row
      }
    }
  }
  int b_ = bm >> 12;
  if (sel < 2) {
    const float* bias = (sel == 0) ? bq : bk;
    bf16* base = (sel == 0) ? Qb : Kb;
    #pragma unroll
    for (int mt = 0; mt < 4; ++mt) {
      int t = (bm & 4095) + wr * 64 + mt * 16 + lo;
      #pragma unroll
      for (int nt = 0; nt < 4; ++nt) {
        int n0 = (bn + wc * 64 + nt * 16 + quad * 4) & 511;
        int h = n0 >> 6, dh0 = n0 & 63;
        bf16x4_t v;
        #pragma unroll
        for (int r = 0; r < 4; ++r) {
          float bs = bias[n0 + r];
          if (sel == 0) bs *= QSCALE;
          v[r] = (bf16)(acc[mt][nt][r] + bs);
        }
        *(bf16x4_t*)(base + (size_t)(b_ * H_ + h) * T_ * DH_ +
                     (size_t)t * 64 + dh0) = v;
      }
    }
  } else {
    #pragma unroll
    for (int nt = 0; nt < 4; ++nt) {
      int n0 = (bn + wc * 64 + nt * 16 + lo) & 511;
      int h = n0 >> 6, dh = n0 & 63;
      float bs = bv[n0];
      #pragma unroll
      for (int mt = 0; mt < 4; ++mt) {
        int t0 = (bm & 4095) + wr * 64 + mt * 16 + quad * 4;
        bf16x4_t v;
        #pragma unroll
        for (int r = 0; r < 4; ++r) v[r] = (bf16)(acc[mt][nt][r] + bs);
        *(bf16x4_t*)(Vtb + ((size_t)(b_ * H_ + h) * DH_ + dh) * T_ + t0) = v;
      }
    }
  }
}

// ------------------------------------------------------ flash attention ----
// Cross-chunk software pipeline: per iteration j (one 64-key chunk):
//   [QK(j+1) MFMA]  <- independent of chunk-j VALU -> overlaps in pipes
//   [stage K(j+2), V(j+1), mask(j+1)]
//   [mask/exp2/pack(j) VALU]   (runs while QK(j+1) drains the matrix pipe)
//   [rowsum+PV(j) MFMA]
//   [vmcnt(0); s_barrier]      (loads issued ~550cy earlier -> near-free)
// K triple-buffered, V double-buffered (40KB LDS = 4 blocks/CU exactly).
// St ping-pong (StA/StB) with static naming; zero C-in at ks==0 (no re-zero).
// WAR safety: every LDS overwrite is >=1 barrier after its last read.
#define SWZ(r) (((r) & 3) | ((((r) >> 3) & 1) << 2))

__global__ __launch_bounds__(256, 4) void attn_kernel(
    const bf16* __restrict__ Qb, const bf16* __restrict__ Kb,
    const bf16* __restrict__ Vtb, const u32* __restrict__ bm2,
    bf16* __restrict__ Obuf)
{
  __shared__ char smem[40960];
  char* k0 = smem;                      // K(j) with j%3==0
  char* k1 = smem + 8192;
  char* k2 = smem + 16384;
  char* v0 = smem + 24576;              // V(j) with j%2==0
  char* v1 = smem + 32768;
  int tid = threadIdx.x;
  int lane = tid & 63, wave = tid >> 6;
  int lo = lane & 15, quad = lane >> 4;
  int qh = wave & 1, kh = wave >> 1;
  int blk = blockIdx.x;
  int bh = blk & 15;                    // XCD-aware: bh pinned per XCD
  int qt64 = blk >> 4;
  int qbase = qt64 * 64;

  const bf16* Kg = Kb + (size_t)bh * T_ * DH_;
  const bf16* Vg = Vtb + (size_t)bh * DH_ * T_;
  const u32* mg = bm2 + (size_t)qt64 * 8192;

  // preload Q fragments (loop-invariant); B operand of mfma(K,Q)
  const bf16* Qg = Qb + ((size_t)bh * T_ + qbase + qh * 32) * DH_;
  bf16x8_t qf[2][2];
  #pragma unroll
  for (int qt = 0; qt < 2; ++qt)
    #pragma unroll
    for (int ks = 0; ks < 2; ++ks)
      qf[qt][ks] = *(const bf16x8_t*)(Qg + (qt * 16 + lo) * 64 + ks * 32 + quad * 8);

  // ones-column B-frag for K=32 rowsum MFMA (col n=0 -> lanes lo==0)
  bf16 onev = (lo == 0) ? (bf16)1.0f : (bf16)0.0f;
  bf16x8_t ones8 = {onev, onev, onev, onev, onev, onev, onev, onev};

  f32x4 O[2][4] = {};
  f32x4 Ol[2] = {};

  auto stageK = [&](int kc, char* buf) {
    #pragma unroll
    for (int i = 0; i < 2; ++i) {
      int s = tid + i * 256;
      int row = s >> 3, slot = s & 7;
      int cg = slot ^ SWZ(row);
      async16(buf + s * 16, Kg + (size_t)(kc * 64 + row) * 64 + cg * 8);
    }
  };
  auto stageV = [&](int kc, char* buf) {
    #pragma unroll
    for (int i = 0; i < 2; ++i) {
      int s = tid + i * 256;
      int row = s >> 3, slot = s & 7;
      int cg = slot ^ SWZ(row);
      async16(buf + s * 16, Vg + (size_t)row * T_ + kc * 64 + cg * 8);
    }
  };
  auto mload = [&](int kc, int qt) -> u32 {
    return mg[kc * 128 + (qh * 32 + qt * 16 + lo) * 2 + kh];
  };
  // S^T = K Q^T; permuted K-row feed: krow = kh*32 + (lo>>2)*8 + kt*4 + (lo&3)
  //  -> St[kt][qt][r] holds k = kh*32 + quad*8 + kt*4 + r
  auto qk = [&](const char* bK, f32x4 (&St)[2][2]) {
    __builtin_amdgcn_s_setprio(1);
    #pragma unroll
    for (int ks = 0; ks < 2; ++ks)
      #pragma unroll
      for (int kt = 0; kt < 2; ++kt) {
        int krow = kh * 32 + ((lo >> 2) << 3) + kt * 4 + (lo & 3);
        int ch = (ks * 4 + quad) ^ SWZ(krow);
        bf16x8_t kf = *(const bf16x8_t*)(bK + krow * 128 + ch * 16);
        #pragma unroll
        for (int qt = 0; qt < 2; ++qt) {
          f32x4 cin = (ks == 0) ? (f32x4){0.f, 0.f, 0.f, 0.f} : St[kt][qt];
          St[kt][qt] = __builtin_amdgcn_mfma_f32_16x16x32_bf16(
              kf, qf[qt][ks], cin, 0, 0, 0);
        }
      }
    __builtin_amdgcn_s_setprio(0);
  };
  auto finish = [&](const char* bV, const f32x4 (&St)[2][2], u32 w0, u32 w1) {
    // mask (sbfe + and) + exp2 + pack to K=32 PV A-frags
    bf16x8_t pf8[2];
    #pragma unroll
    for (int qt = 0; qt < 2; ++qt) {
      u32 w = (qt == 0) ? w0 : w1;
      bf16x8_t t;
      #pragma unroll
      for (int kt = 0; kt < 2; ++kt)
        #pragma unroll
        for (int r = 0; r < 4; ++r) {
          int bit = quad * 8 + kt * 4 + r;
          int mb = ((int)(w << (31 - bit))) >> 31;
          u32 pe = __builtin_bit_cast(u32, __builtin_amdgcn_exp2f(St[kt][qt][r]));
          t[kt * 4 + r] = (bf16)__builtin_bit_cast(float, pe & (u32)mb);
        }
      pf8[qt] = t;
    }
    __builtin_amdgcn_s_setprio(1);
    #pragma unroll
    for (int qt = 0; qt < 2; ++qt)
      Ol[qt] = __builtin_amdgcn_mfma_f32_16x16x32_bf16(
          pf8[qt], ones8, Ol[qt], 0, 0, 0);
    #pragma unroll
    for (int dt = 0; dt < 4; ++dt) {
      int d = dt * 16 + lo;
      int c = (kh * 4 + quad) ^ SWZ(d);
      bf16x8_t vf = *(const bf16x8_t*)(bV + d * 128 + c * 16);
      #pragma unroll
      for (int qt = 0; qt < 2; ++qt)
        O[qt][dt] = __builtin_amdgcn_mfma_f32_16x16x32_bf16(
            pf8[qt], vf, O[qt][dt], 0, 0, 0);
    }
    __builtin_amdgcn_s_setprio(0);
  };

  // prologue: K(0),K(1),V(0),mask(0)
  stageK(0, k0); stageK(1, k1);
  stageV(0, v0);
  u32 wA0 = mload(0, 0), wA1 = mload(0, 1);
  asm volatile("s_waitcnt vmcnt(0)" ::: "memory");
  __builtin_amdgcn_s_barrier();
  f32x4 StA[2][2], StB[2][2];
  qk(k0, StA);                           // QK(0)
  // iter-j invariants: kRd=buf[(j+1)%3], kWr=buf[(j+2)%3], kOld=buf[j%3];
  //                    vRd=buf[j&1], vWr=buf[(j+1)&1]
  char* kRd = k1; char* kWr = k2; char* kOld = k0;
  char* vRd = v0; char* vWr = v1;
  u32 wB0 = 0, wB1 = 0;
  #pragma unroll 1
  for (int jj = 0; jj < 32; ++jj) {
    int j0 = 2 * jj, j1 = j0 + 1;
    // ---- body even: consume StA/wA(j0), produce StB/wB(j0+1)
    if (j0 <= 62) qk(kRd, StB);                      // QK(j0+1)
    if (j0 <= 61) stageK(j0 + 2, kWr);
    if (j0 <= 62) { stageV(j0 + 1, vWr); wB0 = mload(j0 + 1, 0); wB1 = mload(j0 + 1, 1); }
    finish(vRd, StA, wA0, wA1);                      // chunk j0
    asm volatile("s_waitcnt vmcnt(0)" ::: "memory");
    __builtin_amdgcn_s_barrier();
    { char* t = kRd; kRd = kWr; kWr = kOld; kOld = t; }
    { char* t = vRd; vRd = vWr; vWr = t; }
    // ---- body odd: consume StB/wB(j1), produce StA/wA(j1+1)
    if (j1 <= 62) qk(kRd, StA);                      // QK(j1+1)
    if (j1 <= 61) stageK(j1 + 2, kWr);
    if (j1 <= 62) { stageV(j1 + 1, vWr); wA0 = mload(j1 + 1, 0); wA1 = mload(j1 + 1, 1); }
    finish(vRd, StB, wB0, wB1);                      // chunk j1
    asm volatile("s_waitcnt vmcnt(0)" ::: "memory");
    __builtin_amdgcn_s_barrier();
    { char* t = kRd; kRd = kWr; kWr = kOld; kOld = t; }
    { char* t = vRd; vRd = vWr; vWr = t; }
  }

  // ---- epilogue: rowsums in lanes lo==0 of Ol; combine kh pair ----
  __syncthreads();
  float* smO = (float*)smem;            // 64 x 64 f32 = 16 KB (reuses K bufs)
  float* smLa = (float*)(smem + 16384); // rowsum partials kh=0
  float* smLb = (float*)(smem + 16640); // rowsum partials kh=1
  if (lo == 0) {
    float* dst = (kh == 0) ? smLa : smLb;
    #pragma unroll
    for (int qt = 0; qt < 2; ++qt)
      #pragma unroll
      for (int r = 0; r < 4; ++r)
        dst[qh * 32 + qt * 16 + quad * 4 + r] = Ol[qt][r];
  }
  if (kh == 1) {
    #pragma unroll
    for (int qt = 0; qt < 2; ++qt)
      #pragma unroll
      for (int dt = 0; dt < 4; ++dt)
        #pragma unroll
        for (int r = 0; r < 4; ++r)
          smO[(qh * 32 + qt * 16 + quad * 4 + r) * 64 + dt * 16 + lo] = O[qt][dt][r];
  }
  __syncthreads();
  if (kh == 0) {
    bf16* Og = Obuf + ((size_t)bh * T_ + qbase + qh * 32) * DH_;
    #pragma unroll
    for (int qt = 0; qt < 2; ++qt) {
      #pragma unroll
      for (int r = 0; r < 4; ++r) {
        int rl = qt * 16 + quad * 4 + r;
        float inv = 1.0f / (smLa[qh * 32 + rl] + smLb[qh * 32 + rl]);
        #pragma unroll
        for (int dt = 0; dt < 4; ++dt) {
          float o = (O[qt][dt][r] + smO[(qh * 32 + rl) * 64 + dt * 16 + lo]) * inv;
          Og[(size_t)rl * 64 + dt * 16 + lo] = (bf16)o;
        }
      }
    }
  }
}

// ------------------------------------------------------ output proj --------
// 64x64 tiles, operand-swapped -> float4 stores.
__global__ __launch_bounds__(256) void proj_kernel(
    const bf16* __restrict__ Obuf, const bf16* __restrict__ WoT,
    const float* __restrict__ bo, float* __restrict__ out)
{
  __shared__ char smem[16384];
  char* smA = smem;
  char* smW = smem + 8192;
  int tid = threadIdx.x;
  int lane = tid & 63, wave = tid >> 6;
  int lo = lane & 15, quad = lane >> 4;
  int wr = wave >> 1, wc = wave & 1;
  int bm = blockIdx.x * 64;
  int bn = blockIdx.y * 64;
  int b_ = bm >> 12, trow = bm & 4095;
  f32x4 acc[2][2] = {};
  for (int kc = 0; kc < 8; ++kc) {
    __syncthreads();
    const bf16* Ag = Obuf + ((size_t)(b_ * H_ + kc) * T_ + trow) * DH_;
    for (int s = tid; s < 512; s += 256) {
      int row = s >> 3, slot = s & 7;
      int cg = slot ^ (row & 7) ^ ((row >> 3) & 1);
      async16(smA + s * 16, Ag + row * 64 + cg * 8);
      async16(smW + s * 16, WoT + (size_t)(bn + row) * 512 + kc * 64 + cg * 8);
    }
    __syncthreads();
    #pragma unroll
    for (int ks = 0; ks < 2; ++ks) {
      bf16x8_t a[2], b[2];
      #pragma unroll
      for (int mt = 0; mt < 2; ++mt) {
        int row = wr * 32 + mt * 16 + lo;
        int ch = (ks * 4 + quad) ^ (row & 7) ^ ((row >> 3) & 1);
        a[mt] = *(const bf16x8_t*)(smA + row * 128 + ch * 16);
      }
      #pragma unroll
      for (int nt = 0; nt < 2; ++nt) {
        int row = wc * 32 + nt * 16 + lo;
        int ch = (ks * 4 + quad) ^ (row & 7) ^ ((row >> 3) & 1);
        b[nt] = *(const bf16x8_t*)(smW + row * 128 + ch * 16);
      }
      #pragma unroll
      for (int mt = 0; mt < 2; ++mt)
        #pragma unroll
        for (int nt = 0; nt < 2; ++nt)
          acc[mt][nt] = __builtin_amdgcn_mfma_f32_16x16x32_bf16(
              b[nt], a[mt], acc[mt][nt], 0, 0, 0);   // D: m=out-col, n=t
    }
  }
  #pragma unroll
  for (int mt = 0; mt < 2; ++mt) {
    int t = bm + wr * 32 + mt * 16 + lo;
    #pragma unroll
    for (int nt = 0; nt < 2; ++nt) {
      int c0 = bn + wc * 32 + nt * 16 + quad * 4;
      float4 v;
      v.x = acc[mt][nt][0] + bo[c0 + 0];
      v.y = acc[mt][nt][1] + bo[c0 + 1];
      v.z = acc[mt][nt][2] + bo[c0 + 2];
      v.w = acc[mt][nt][3] + bo[c0 + 3];
      *(float4*)(out + (size_t)t * 512 + c0) = v;
    }
  }
}

// --------------------------------------------------------------- launch ----
extern "C" void kernel_launch(void* const* d_in, const int* in_sizes, int n_in,
                              void* d_out, int out_size, void* d_ws, size_t ws_size,
                              hipStream_t stream) {
  const float* x  = (const float*)d_in[0];
  const float* Wq = (const float*)d_in[1];
  const float* bq = (const float*)d_in[2];
  const float* Wk = (const float*)d_in[3];
  const float* bk = (const float*)d_in[4];
  const float* Wv = (const float*)d_in[5];
  const float* bv = (const float*)d_in[6];
  const float* Wo = (const float*)d_in[7];
  const float* bo = (const float*)d_in[8];
  const void* maskp = d_in[9];
  float* out = (float*)d_out;

  char* w = (char*)d_ws;
  bf16* xb    = (bf16*)(w);              //  8,388,608 B
  bf16* WTall = (bf16*)(w + 8388608);    //  1,572,864 B
  bf16* WoT   = (bf16*)(w + 9961472);    //    524,288 B
  bf16* Qb    = (bf16*)(w + 10485760);   //  8,388,608 B
  bf16* Kb    = (bf16*)(w + 18874368);   //  8,388,608 B
  bf16* Vtb   = (bf16*)(w + 27262976);   //  8,388,608 B  (B,H,64,T)
  bf16* Obuf  = (bf16*)(w + 35651584);   //  8,388,608 B
  u32*  bmask = (u32*)(w + 44040192);    //  2,097,152 B

  prep_kernel<<<10240, 256, 0, stream>>>(x, Wq, Wk, Wv, Wo, maskp,
                                         xb, WTall, WoT, bmask);
  qkv_kernel<<<dim3(64, 12), 256, 0, stream>>>(xb, WTall, bq, bk, bv,
                                               Qb, Kb, Vtb);
  attn_kernel<<<1024, 256, 0, stream>>>(Qb, Kb, Vtb, bmask, Obuf);
  proj_kernel<<<dim3(128, 8), 256, 0, stream>>>(Obuf, WoT, bo, out);
}

// Round 4
// 268.120 us; speedup vs baseline: 1.4758x; 1.4758x over previous
//
#include <hip/hip_runtime.h>
#include <stdint.h>

#define B_ 2
#define T_ 4096
#define D_ 512
#define H_ 8
#define DH_ 64

typedef __bf16 bf16;
typedef __bf16 bf16x4_t __attribute__((ext_vector_type(4)));
typedef __bf16 bf16x8_t __attribute__((ext_vector_type(8)));
typedef float f32x4 __attribute__((ext_vector_type(4)));
typedef short short4_t __attribute__((ext_vector_type(4)));
typedef uint32_t u32;

static constexpr float QSCALE = 0.18033688011112042f;   // log2(e)/8 (folded into Wq,bq)

__device__ __forceinline__ void async16(void* lds, const void* g) {
  __builtin_amdgcn_global_load_lds(
      (const __attribute__((address_space(1))) void*)g,
      (__attribute__((address_space(3))) void*)lds, 16, 0, 0);
}

// ---------------------------------------------------------------- prep ----
__global__ __launch_bounds__(256) void prep_kernel(
    const float* __restrict__ x,
    const float* __restrict__ Wq, const float* __restrict__ Wk,
    const float* __restrict__ Wv, const float* __restrict__ Wo,
    const void* __restrict__ maskp,
    bf16* __restrict__ xb, bf16* __restrict__ WTall, bf16* __restrict__ WoT,
    u32* __restrict__ bmask)
{
  int bid = blockIdx.x;
  int tid = threadIdx.x;
  if (bid < 4096) {
    int idx = bid * 256 + tid;
    const float4* xf = (const float4*)x;
    float4 v = xf[idx];
    bf16x4_t o;
    o[0] = (bf16)v.x; o[1] = (bf16)v.y; o[2] = (bf16)v.z; o[3] = (bf16)v.w;
    ((bf16x4_t*)xb)[idx] = o;
  } else if (bid < 8192) {
    int gid = (bid - 4096) * 256 + tid;
    int sel = gid >> 18;
    int idx = gid & 262143;
    int n = idx >> 9, k = idx & 511;
    if (sel < 3) {
      const float* W = (sel == 0) ? Wq : (sel == 1) ? Wk : Wv;
      float v = W[k * 512 + n];
      if (sel == 0) v *= QSCALE;
      WTall[gid] = (bf16)v;
    } else {
      WoT[idx] = (bf16)Wo[k * 512 + n];
    }
  } else {
    int wid = (bid - 8192) * 256 + tid;   // 524,288 words
    const uint8_t* m8 = (const uint8_t*)maskp;
    bool u8mode = (__ballot(m8[4 * (tid & 63) + 1] != 0) != 0ull);
    int row = wid >> 7, wcol = wid & 127;
    size_t off = (size_t)row * 4096 + (size_t)wcol * 32;
    u32 w = 0;
    if (u8mode) {
      const uint4* p = (const uint4*)(m8 + off);
      uint4 a = p[0], b = p[1];
      u32 ws[8] = {a.x, a.y, a.z, a.w, b.x, b.y, b.z, b.w};
      #pragma unroll
      for (int j = 0; j < 32; ++j)
        if ((ws[j >> 2] >> ((j & 3) * 8)) & 0xffu) w |= (1u << j);
    } else {
      const uint4* p = (const uint4*)((const u32*)maskp + off);
      #pragma unroll
      for (int q = 0; q < 8; ++q) {
        uint4 a = p[q];
        if (a.x) w |= 1u << (q * 4 + 0);
        if (a.y) w |= 1u << (q * 4 + 1);
        if (a.z) w |= 1u << (q * 4 + 2);
        if (a.w) w |= 1u << (q * 4 + 3);
      }
    }
    bmask[((size_t)(row >> 6) * 64 + (wcol >> 1)) * 128 + (row & 63) * 2 + (wcol & 1)] = w;
  }
}

// ---------------------------------------------------------- QKV GEMM -------
// 128x128 tiles: 4 waves, each owns a 64x64 sub-tile. BK=64, 2-barrier.
// NEW: LDS-transpose epilogue -> fully coalesced 16B output stores
// (old path: 8B/lane at 128B stride for Q/K, 8KB stride for V).
__global__ __launch_bounds__(256) void qkv_kernel(
    const bf16* __restrict__ xb, const bf16* __restrict__ WTall,
    const float* __restrict__ bq, const float* __restrict__ bk,
    const float* __restrict__ bv,
    bf16* __restrict__ Qb, bf16* __restrict__ Kb, bf16* __restrict__ Vtb)
{
  __shared__ char smem[32768];
  char* smX = smem;                 // 128 rows x 128B (swizzled)
  char* smW = smem + 16384;         // 128 rows x 128B
  int tid = threadIdx.x;
  int lane = tid & 63, wave = tid >> 6;
  int lo = lane & 15, quad = lane >> 4;
  int wr = wave >> 1, wc = wave & 1;
  int bm = blockIdx.x * 128;
  int bn = blockIdx.y * 128;
  int sel = bn >> 9;   // 0=Q 1=K 2=V
  f32x4 acc[4][4] = {};
  for (int kc = 0; kc < 8; ++kc) {
    __syncthreads();
    #pragma unroll
    for (int i = 0; i < 4; ++i) {
      int s = tid + i * 256;
      int row = s >> 3, slot = s & 7;
      int cg = slot ^ (row & 7) ^ ((row >> 3) & 1);
      async16(smX + s * 16, xb + (size_t)(bm + row) * 512 + kc * 64 + cg * 8);
      async16(smW + s * 16, WTall + (size_t)(bn + row) * 512 + kc * 64 + cg * 8);
    }
    __syncthreads();
    #pragma unroll
    for (int ks = 0; ks < 2; ++ks) {
      bf16x8_t a[4], b[4];
      #pragma unroll
      for (int mt = 0; mt < 4; ++mt) {
        int row = wr * 64 + mt * 16 + lo;
        int ch = (ks * 4 + quad) ^ (row & 7) ^ ((row >> 3) & 1);
        a[mt] = *(const bf16x8_t*)(smX + row * 128 + ch * 16);
      }
      #pragma unroll
      for (int nt = 0; nt < 4; ++nt) {
        int row = wc * 64 + nt * 16 + lo;
        int ch = (ks * 4 + quad) ^ (row & 7) ^ ((row >> 3) & 1);
        b[nt] = *(const bf16x8_t*)(smW + row * 128 + ch * 16);
      }
      if (sel < 2) {
        #pragma unroll
        for (int mt = 0; mt < 4; ++mt)
          #pragma unroll
          for (int nt = 0; nt < 4; ++nt)
            acc[mt][nt] = __builtin_amdgcn_mfma_f32_16x16x32_bf16(
                b[nt], a[mt], acc[mt][nt], 0, 0, 0);   // D: m=W-row, n=t
      } else {
        #pragma unroll
        for (int mt = 0; mt < 4; ++mt)
          #pragma unroll
          for (int nt = 0; nt < 4; ++nt)
            acc[mt][nt] = __builtin_amdgcn_mfma_f32_16x16x32_bf16(
                a[mt], b[nt], acc[mt][nt], 0, 0, 0);   // D: m=t, n=W-row
      }
    }
  }
  int b_ = bm >> 12;
  // ---- epilogue: acc -> swizzled LDS tile -> coalesced 16B copy-out ----
  __syncthreads();                      // all waves done reading smX/smW
  char* smT = smem;                     // 128x128 bf16 = 32768 B, chunk-swizzled
  if (sel < 2) {
    const float* bias = (sel == 0) ? bq : bk;
    bf16* base = (sel == 0) ? Qb : Kb;
    // lane holds acc[mt][nt][r] at tile-local t = wr*64+mt*16+lo,
    // col = wc*64+nt*16+quad*4+r. LDS tile layout [t][col] bf16 (256B rows,
    // 16B chunks swizzled: chunk ^= (t&15)).
    #pragma unroll
    for (int mt = 0; mt < 4; ++mt) {
      int tl = wr * 64 + mt * 16 + lo;
      #pragma unroll
      for (int nt = 0; nt < 4; ++nt) {
        int c0 = wc * 64 + nt * 16 + quad * 4;
        bf16x4_t v;
        #pragma unroll
        for (int r = 0; r < 4; ++r) {
          float bs = bias[(bn & 511) + c0 + r];
          if (sel == 0) bs *= QSCALE;
          v[r] = (bf16)(acc[mt][nt][r] + bs);
        }
        int chunk = (c0 >> 3) ^ (tl & 15);
        int half = (c0 >> 2) & 1;
        *(bf16x4_t*)(smT + tl * 256 + chunk * 16 + half * 8) = v;
      }
    }
    __syncthreads();
    #pragma unroll
    for (int it = 0; it < 8; ++it) {
      int i = tid + it * 256;
      int tl = i >> 4, c = i & 15;
      bf16x8_t v = *(const bf16x8_t*)(smT + tl * 256 + ((c ^ (tl & 15)) * 16));
      int colg = (bn & 511) + c * 8;
      int h = colg >> 6, dh0 = colg & 63;
      int t = (bm & 4095) + tl;
      *(bf16x8_t*)(base + (size_t)(b_ * H_ + h) * T_ * DH_ +
                   (size_t)t * 64 + dh0) = v;
    }
  } else {
    // lane holds acc[mt][nt][r] at tile-local t = wr*64+mt*16+quad*4+r,
    // dh-row = wc*64+nt*16+lo. LDS tile [dh][t] bf16.
    #pragma unroll
    for (int nt = 0; nt < 4; ++nt) {
      int dhl = wc * 64 + nt * 16 + lo;
      float bs = bv[(bn & 511) + dhl];
      #pragma unroll
      for (int mt = 0; mt < 4; ++mt) {
        int t0 = wr * 64 + mt * 16 + quad * 4;
        bf16x4_t v;
        #pragma unroll
        for (int r = 0; r < 4; ++r) v[r] = (bf16)(acc[mt][nt][r] + bs);
        int chunk = (t0 >> 3) ^ (dhl & 15);
        int half = (t0 >> 2) & 1;
        *(bf16x4_t*)(smT + dhl * 256 + chunk * 16 + half * 8) = v;
      }
    }
    __syncthreads();
    #pragma unroll
    for (int it = 0; it < 8; ++it) {
      int i = tid + it * 256;
      int dhl = i >> 4, c = i & 15;
      bf16x8_t v = *(const bf16x8_t*)(smT + dhl * 256 + ((c ^ (dhl & 15)) * 16));
      int colg = (bn & 511) + dhl;
      int h = colg >> 6, dh = colg & 63;
      int t = (bm & 4095) + c * 8;
      *(bf16x8_t*)(Vtb + ((size_t)(b_ * H_ + h) * DH_ + dh) * T_ + t) = v;
    }
  }
}

// ------------------------------------------------------ flash attention ----
// one WG per (b,h, 64-row q-tile); wave (qh,kh) = 32q x 32k; 64-key chunks,
// two-barrier single-buffer staging (round-1 proven structure, 109us).
// XCD-aware bh binding: bh = blk&15 -> each XCD serves 2 bh (K/V fit its L2).
// S^T = mfma(K,Q) with PERMUTED K-row feed so St[kt][qt][r] sits at
// k = quad*8 + kt*4 + r -> P fragments concatenate into a 16x16x32 A-frag;
// PV + rowsum run on mfma_f32_16x16x32_bf16.
// NEW vs round 1: final O store goes through an 8KB LDS bf16 buffer ->
// one fully-coalesced 16B-per-lane copy-out (was 2B scalar scattered).
#define SWZ(r) (((r) & 3) | ((((r) >> 3) & 1) << 2))

__global__ __launch_bounds__(256, 4) void attn_kernel(
    const bf16* __restrict__ Qb, const bf16* __restrict__ Kb,
    const bf16* __restrict__ Vtb, const u32* __restrict__ bm2,
    bf16* __restrict__ Obuf)
{
  __shared__ char smem[25600];
  char* smK = smem;                     // 8192: 64 key-rows x 128B (swizzled)
  char* smV = smem + 8192;              // 8192: 64 d-rows x 128B (swizzled)
  u32* smM = (u32*)(smem + 16384);      // 512B mask words
  float* smLa = (float*)(smem + 16896); // 256B rowsum partials kh=0
  float* smLb = (float*)(smem + 17152); // 256B rowsum partials kh=1
  bf16* smOut = (bf16*)(smem + 17408);  // 8192B final bf16 out tile
  int tid = threadIdx.x;
  int lane = tid & 63, wave = tid >> 6;
  int lo = lane & 15, quad = lane >> 4;
  int qh = wave & 1, kh = wave >> 1;
  int blk = blockIdx.x;
  int bh = blk & 15;                    // XCD-aware: bh pinned per XCD
  int qt64 = blk >> 4;
  int qbase = qt64 * 64;

  const bf16* Kg = Kb + (size_t)bh * T_ * DH_;
  const bf16* Vg = Vtb + (size_t)bh * DH_ * T_;
  const u32* mg = bm2 + (size_t)qt64 * 8192;

  // preload Q fragments (loop-invariant); B operand of mfma(K,Q)
  const bf16* Qg = Qb + ((size_t)bh * T_ + qbase + qh * 32) * DH_;
  bf16x8_t qf[2][2];
  #pragma unroll
  for (int qt = 0; qt < 2; ++qt)
    #pragma unroll
    for (int ks = 0; ks < 2; ++ks)
      qf[qt][ks] = *(const bf16x8_t*)(Qg + (qt * 16 + lo) * 64 + ks * 32 + quad * 8);

  // ones-column B-frag for K=32 rowsum MFMA (col n=0 -> lanes lo==0)
  bf16 onev = (lo == 0) ? (bf16)1.0f : (bf16)0.0f;
  bf16x8_t ones8 = {onev, onev, onev, onev, onev, onev, onev, onev};

  f32x4 O[2][4] = {};
  f32x4 Ol[2] = {};

  for (int kc = 0; kc < 64; ++kc) {
    __syncthreads();                    // prior compute done: safe to restage
    #pragma unroll
    for (int i = 0; i < 2; ++i) {
      int s = tid + i * 256;
      int row = s >> 3, slot = s & 7;
      int cg = slot ^ SWZ(row);
      async16(smK + s * 16, Kg + (size_t)(kc * 64 + row) * 64 + cg * 8);
      async16(smV + s * 16, Vg + (size_t)row * T_ + kc * 64 + cg * 8);
    }
    if (tid < 32) async16((char*)smM + tid * 16, mg + kc * 128 + tid * 4);
    __syncthreads();                    // staging visible
    // S^T = K Q^T (32k x 32q per wave); permuted K-row feed:
    // krow = kh*32 + (lo>>2)*8 + kt*4 + (lo&3)
    //  -> St[kt][qt][r] holds k = kh*32 + quad*8 + kt*4 + r
    f32x4 St[2][2] = {};
    __builtin_amdgcn_s_setprio(1);
    #pragma unroll
    for (int ks = 0; ks < 2; ++ks)
      #pragma unroll
      for (int kt = 0; kt < 2; ++kt) {
        int krow = kh * 32 + ((lo >> 2) << 3) + kt * 4 + (lo & 3);
        int ch = (ks * 4 + quad) ^ SWZ(krow);
        bf16x8_t kf = *(const bf16x8_t*)(smK + krow * 128 + ch * 16);
        #pragma unroll
        for (int qt = 0; qt < 2; ++qt)
          St[kt][qt] = __builtin_amdgcn_mfma_f32_16x16x32_bf16(
              kf, qf[qt][ks], St[kt][qt], 0, 0, 0);
      }
    __builtin_amdgcn_s_setprio(0);
    // mask (sext bitfield + AND) + exp2 + pack to K=32 PV A-frags
    bf16x8_t pf8[2];   // [qt]: elem j=kt*4+r -> k = kh*32 + quad*8 + j
    #pragma unroll
    for (int qt = 0; qt < 2; ++qt) {
      u32 w = smM[(qh * 32 + qt * 16 + lo) * 2 + kh];
      bf16x8_t t;
      #pragma unroll
      for (int kt = 0; kt < 2; ++kt)
        #pragma unroll
        for (int r = 0; r < 4; ++r) {
          int bit = quad * 8 + kt * 4 + r;
          int mb = ((int)(w << (31 - bit))) >> 31;
          u32 pe = __builtin_bit_cast(u32, __builtin_amdgcn_exp2f(St[kt][qt][r]));
          t[kt * 4 + r] = (bf16)__builtin_bit_cast(float, pe & (u32)mb);
        }
      pf8[qt] = t;
    }
    __builtin_amdgcn_s_setprio(1);
    // rowsum via ones-column on the MFMA pipe (K=32)
    #pragma unroll
    for (int qt = 0; qt < 2; ++qt)
      Ol[qt] = __builtin_amdgcn_mfma_f32_16x16x32_bf16(
          pf8[qt], ones8, Ol[qt], 0, 0, 0);
    // O += P V  (K=32: one b128 V read per dt, one MFMA per (qt,dt))
    #pragma unroll
    for (int dt = 0; dt < 4; ++dt) {
      int d = dt * 16 + lo;
      int c = (kh * 4 + quad) ^ SWZ(d);
      bf16x8_t vf = *(const bf16x8_t*)(smV + d * 128 + c * 16);
      #pragma unroll
      for (int qt = 0; qt < 2; ++qt)
        O[qt][dt] = __builtin_amdgcn_mfma_f32_16x16x32_bf16(
            pf8[qt], vf, O[qt][dt], 0, 0, 0);
    }
    __builtin_amdgcn_s_setprio(0);
  }
  // ---- epilogue: rowsums in lanes lo==0 of Ol; combine kh pair ----
  __syncthreads();
  float* smO = (float*)smem;       // 64 x 64 f32 = 16 KB (reuses smK/smV)
  if (lo == 0) {
    float* dst = (kh == 0) ? smLa : smLb;
    #pragma unroll
    for (int qt = 0; qt < 2; ++qt)
      #pragma unroll
      for (int r = 0; r < 4; ++r)
        dst[qh * 32 + qt * 16 + quad * 4 + r] = Ol[qt][r];
  }
  if (kh == 1) {
    #pragma unroll
    for (int qt = 0; qt < 2; ++qt)
      #pragma unroll
      for (int dt = 0; dt < 4; ++dt)
        #pragma unroll
        for (int r = 0; r < 4; ++r)
          smO[(qh * 32 + qt * 16 + quad * 4 + r) * 64 + dt * 16 + lo] = O[qt][dt][r];
  }
  __syncthreads();
  if (kh == 0) {
    #pragma unroll
    for (int qt = 0; qt < 2; ++qt) {
      #pragma unroll
      for (int r = 0; r < 4; ++r) {
        int rl = qt * 16 + quad * 4 + r;
        float inv = 1.0f / (smLa[qh * 32 + rl] + smLb[qh * 32 + rl]);
        #pragma unroll
        for (int dt = 0; dt < 4; ++dt) {
          float o = (O[qt][dt][r] + smO[(qh * 32 + rl) * 64 + dt * 16 + lo]) * inv;
          smOut[(qh * 32 + rl) * 64 + dt * 16 + lo] = (bf16)o;
        }
      }
    }
  }
  __syncthreads();
  // coalesced copy-out: 8192B contiguous block, 16B per lane
  {
    bf16* Og = Obuf + ((size_t)bh * T_ + qbase) * DH_;
    #pragma unroll
    for (int it = 0; it < 2; ++it) {
      int i = tid + it * 256;
      *(bf16x8_t*)(Og + i * 8) = *(const bf16x8_t*)(smOut + i * 8);
    }
  }
}

// ------------------------------------------------------ output proj --------
// 64x64 tiles, operand-swapped. NEW: LDS-transpose epilogue -> coalesced
// 16B stores (was 16B/lane at 2KB stride).
__global__ __launch_bounds__(256) void proj_kernel(
    const bf16* __restrict__ Obuf, const bf16* __restrict__ WoT,
    const float* __restrict__ bo, float* __restrict__ out)
{
  __shared__ char smem[16384];
  char* smA = smem;
  char* smW = smem + 8192;
  int tid = threadIdx.x;
  int lane = tid & 63, wave = tid >> 6;
  int lo = lane & 15, quad = lane >> 4;
  int wr = wave >> 1, wc = wave & 1;
  int bm = blockIdx.x * 64;
  int bn = blockIdx.y * 64;
  int b_ = bm >> 12, trow = bm & 4095;
  f32x4 acc[2][2] = {};
  for (int kc = 0; kc < 8; ++kc) {
    __syncthreads();
    const bf16* Ag = Obuf + ((size_t)(b_ * H_ + kc) * T_ + trow) * DH_;
    for (int s = tid; s < 512; s += 256) {
      int row = s >> 3, slot = s & 7;
      int cg = slot ^ (row & 7) ^ ((row >> 3) & 1);
      async16(smA + s * 16, Ag + row * 64 + cg * 8);
      async16(smW + s * 16, WoT + (size_t)(bn + row) * 512 + kc * 64 + cg * 8);
    }
    __syncthreads();
    #pragma unroll
    for (int ks = 0; ks < 2; ++ks) {
      bf16x8_t a[2], b[2];
      #pragma unroll
      for (int mt = 0; mt < 2; ++mt) {
        int row = wr * 32 + mt * 16 + lo;
        int ch = (ks * 4 + quad) ^ (row & 7) ^ ((row >> 3) & 1);
        a[mt] = *(const bf16x8_t*)(smA + row * 128 + ch * 16);
      }
      #pragma unroll
      for (int nt = 0; nt < 2; ++nt) {
        int row = wc * 32 + nt * 16 + lo;
        int ch = (ks * 4 + quad) ^ (row & 7) ^ ((row >> 3) & 1);
        b[nt] = *(const bf16x8_t*)(smW + row * 128 + ch * 16);
      }
      #pragma unroll
      for (int mt = 0; mt < 2; ++mt)
        #pragma unroll
        for (int nt = 0; nt < 2; ++nt)
          acc[mt][nt] = __builtin_amdgcn_mfma_f32_16x16x32_bf16(
              b[nt], a[mt], acc[mt][nt], 0, 0, 0);   // D: m=out-col, n=t
    }
  }
  // ---- epilogue: acc -> swizzled LDS f32 tile -> coalesced copy-out ----
  __syncthreads();
  char* smT = smem;                     // 64x64 f32 = 16384 B, 16B chunks swz
  #pragma unroll
  for (int mt = 0; mt < 2; ++mt) {
    int tl = wr * 32 + mt * 16 + lo;
    #pragma unroll
    for (int nt = 0; nt < 2; ++nt) {
      int c0 = wc * 32 + nt * 16 + quad * 4;
      f32x4 v;
      #pragma unroll
      for (int r = 0; r < 4; ++r) v[r] = acc[mt][nt][r] + bo[bn + c0 + r];
      int chunk = (c0 >> 2) ^ (tl & 15);
      *(f32x4*)(smT + tl * 256 + chunk * 16) = v;
    }
  }
  __syncthreads();
  #pragma unroll
  for (int it = 0; it < 4; ++it) {
    int i = tid + it * 256;
    int tl = i >> 4, c = i & 15;
    f32x4 v = *(const f32x4*)(smT + tl * 256 + ((c ^ (tl & 15)) * 16));
    *(f32x4*)(out + (size_t)(bm + tl) * 512 + bn + c * 4) = v;
  }
}

// --------------------------------------------------------------- launch ----
extern "C" void kernel_launch(void* const* d_in, const int* in_sizes, int n_in,
                              void* d_out, int out_size, void* d_ws, size_t ws_size,
                              hipStream_t stream) {
  const float* x  = (const float*)d_in[0];
  const float* Wq = (const float*)d_in[1];
  const float* bq = (const float*)d_in[2];
  const float* Wk = (const float*)d_in[3];
  const float* bk = (const float*)d_in[4];
  const float* Wv = (const float*)d_in[5];
  const float* bv = (const float*)d_in[6];
  const float* Wo = (const float*)d_in[7];
  const float* bo = (const float*)d_in[8];
  const void* maskp = d_in[9];
  float* out = (float*)d_out;

  char* w = (char*)d_ws;
  bf16* xb    = (bf16*)(w);              //  8,388,608 B
  bf16* WTall = (bf16*)(w + 8388608);    //  1,572,864 B
  bf16* WoT   = (bf16*)(w + 9961472);    //    524,288 B
  bf16* Qb    = (bf16*)(w + 10485760);   //  8,388,608 B
  bf16* Kb    = (bf16*)(w + 18874368);   //  8,388,608 B
  bf16* Vtb   = (bf16*)(w + 27262976);   //  8,388,608 B  (B,H,64,T)
  bf16* Obuf  = (bf16*)(w + 35651584);   //  8,388,608 B
  u32*  bmask = (u32*)(w + 44040192);    //  2,097,152 B

  prep_kernel<<<10240, 256, 0, stream>>>(x, Wq, Wk, Wv, Wo, maskp,
                                         xb, WTall, WoT, bmask);
  qkv_kernel<<<dim3(64, 12), 256, 0, stream>>>(xb, WTall, bq, bk, bv,
                                               Qb, Kb, Vtb);
  attn_kernel<<<1024, 256, 0, stream>>>(Qb, Kb, Vtb, bmask, Obuf);
  proj_kernel<<<dim3(128, 8), 256, 0, stream>>>(Obuf, WoT, bo, out);
}